// Round 1
// baseline (194.588 us; speedup 1.0000x reference)
//
#include <hip/hip_runtime.h>
#include <hip/hip_bf16.h>
#include <math.h>

typedef __attribute__((ext_vector_type(8))) __bf16 bf16x8;
typedef __attribute__((ext_vector_type(4))) float f32x4;

#define IN_DIM 2048
#define NH1 128
#define NH2 64
#define KDIM 1024

__device__ inline f32x4 mfma16(bf16x8 a, bf16x8 b, f32x4 c) {
    return __builtin_amdgcn_mfma_f32_16x16x32_bf16(a, b, c, 0, 0, 0);
}

// ---------------------------------------------------------------------------
// prep: permute W1/W2 into MFMA-fragment order (bf16), pack basis rows with
// c_j = head_w[j] * exp(-||b_j||^2).
// Fragment convention (A and B identical): within a 32-k x 16-col tile,
// lane l, elem e  ->  k = (l>>4)*8 + e , col/row = l&15.
// ---------------------------------------------------------------------------
__global__ void prep_kernel(const float* __restrict__ W1,
                            const float* __restrict__ W2,
                            const float* __restrict__ basis,
                            const float* __restrict__ head_w,
                            __bf16* __restrict__ w1f,
                            __bf16* __restrict__ w2f,
                            float* __restrict__ bp) {
    int idx = blockIdx.x * 256 + threadIdx.x;   // 0 .. 262143
    if (idx < IN_DIM * NH1) {
        // layout: ((ks*8 + c) << 9) + l*8 + e ; ks: 64 steps of K=32
        int ks = idx >> 12;
        int rem = idx & 4095;
        int c = rem >> 9;
        int q = rem & 511;
        int l = q >> 3, e = q & 7;
        int k = ks * 32 + ((l >> 4) << 3) + e;
        int col = (c << 4) + (l & 15);
        w1f[idx] = (__bf16)W1[k * NH1 + col];
    }
    if (idx < NH1 * NH2) {
        // layout: ((c2*4 + kb) << 9) + l*8 + e ; kb: 4 steps of K=32
        int cb = idx >> 9;
        int c2 = cb >> 2, kb = cb & 3;
        int q = idx & 511;
        int l = q >> 3, e = q & 7;
        int k = kb * 32 + ((l >> 4) << 3) + e;
        int col = (c2 << 4) + (l & 15);
        w2f[idx] = (__bf16)W2[k * NH2 + col];
    }
    if (idx < KDIM) {
        const float* b = basis + idx * 5;
        float n2 = b[0]*b[0] + b[1]*b[1] + b[2]*b[2] + b[3]*b[3] + b[4]*b[4];
        float* o = bp + idx * 8;
        o[0] = b[0]; o[1] = b[1]; o[2] = b[2]; o[3] = b[3]; o[4] = b[4];
        o[5] = 1.0f;
        o[6] = head_w[idx] * expf(-n2);   // gamma = 1
        o[7] = 0.0f;
    }
}

// ---------------------------------------------------------------------------
// fused main: per wave: 32 rows. GEMM1 (bf16 MFMA, x streamed from HBM),
// GEMM2 (bf16 MFMA via wave-private LDS tile), GEMM3+conv (f32 + shuffles),
// RBF (f32, exp2 form). One block = 4 waves = 128 rows.
// ---------------------------------------------------------------------------
__launch_bounds__(256)
__global__ void fused_main(const float* __restrict__ x,
                           const __bf16* __restrict__ w1f,
                           const float* __restrict__ b1,
                           const __bf16* __restrict__ w2f,
                           const float* __restrict__ b2,
                           const float* __restrict__ W3,
                           const float* __restrict__ b3,
                           const float* __restrict__ conv_k,
                           const float* __restrict__ conv_b,
                           const float* __restrict__ bp,
                           const float* __restrict__ head_b,
                           float* __restrict__ out) {
    __shared__ __bf16 h1s[4][32 * NH1];   // 32 KB, wave-private tiles
    __shared__ float z5s[128][8];         // 4 KB
    __shared__ float psum[128];           // 0.5 KB

    const int tid = threadIdx.x;
    const int w = __builtin_amdgcn_readfirstlane(tid >> 6);
    const int l = tid & 63;
    const int row0 = blockIdx.x * 128 + w * 32;

    // ---------------- stage 1: h1 = relu(x @ W1 + b1), bf16 MFMA ----------
    f32x4 acc[2][8];
#pragma unroll
    for (int g = 0; g < 2; ++g)
#pragma unroll
        for (int c = 0; c < 8; ++c) acc[g][c] = (f32x4){0.f, 0.f, 0.f, 0.f};

    const float* xw0 = x + (size_t)(row0 + (l & 15)) * IN_DIM + ((l >> 4) << 3);
    const float* xw1 = xw0 + (size_t)16 * IN_DIM;
    const __bf16* wbase = w1f + l * 8;

    for (int ks = 0; ks < 64; ++ks) {
        const float* p0 = xw0 + ks * 32;
        const float* p1 = xw1 + ks * 32;
        f32x4 a00 = *(const f32x4*)p0;
        f32x4 a01 = *(const f32x4*)(p0 + 4);
        f32x4 a10 = *(const f32x4*)p1;
        f32x4 a11 = *(const f32x4*)(p1 + 4);
        bf16x8 A0, A1;
        A0[0] = (__bf16)a00.x; A0[1] = (__bf16)a00.y; A0[2] = (__bf16)a00.z; A0[3] = (__bf16)a00.w;
        A0[4] = (__bf16)a01.x; A0[5] = (__bf16)a01.y; A0[6] = (__bf16)a01.z; A0[7] = (__bf16)a01.w;
        A1[0] = (__bf16)a10.x; A1[1] = (__bf16)a10.y; A1[2] = (__bf16)a10.z; A1[3] = (__bf16)a10.w;
        A1[4] = (__bf16)a11.x; A1[5] = (__bf16)a11.y; A1[6] = (__bf16)a11.z; A1[7] = (__bf16)a11.w;
        const __bf16* wp = wbase + ((size_t)ks << 12);
#pragma unroll
        for (int c = 0; c < 8; ++c) {
            bf16x8 B = *(const bf16x8*)(wp + (c << 9));
            acc[0][c] = mfma16(A0, B, acc[0][c]);
            acc[1][c] = mfma16(A1, B, acc[1][c]);
        }
    }

    // epilogue: + b1, relu, bf16, into wave-private LDS tile [32][128]
    float b1v[8];
#pragma unroll
    for (int c = 0; c < 8; ++c) b1v[c] = b1[c * 16 + (l & 15)];
    __bf16* hw1 = &h1s[w][0];
#pragma unroll
    for (int g = 0; g < 2; ++g)
#pragma unroll
        for (int c = 0; c < 8; ++c)
#pragma unroll
            for (int r = 0; r < 4; ++r) {
                int rr = g * 16 + ((l >> 4) << 2) + r;
                int cc = c * 16 + (l & 15);
                hw1[rr * NH1 + cc] = (__bf16)fmaxf(acc[g][c][r] + b1v[c], 0.f);
            }

    __syncthreads();

    // ---------------- stage 2: h2 = relu(h1 @ W2 + b2), bf16 MFMA ---------
    f32x4 acc2[2][4];
#pragma unroll
    for (int g = 0; g < 2; ++g)
#pragma unroll
        for (int c = 0; c < 4; ++c) acc2[g][c] = (f32x4){0.f, 0.f, 0.f, 0.f};

#pragma unroll
    for (int kb = 0; kb < 4; ++kb) {
        bf16x8 A0 = *(const bf16x8*)&hw1[(l & 15) * NH1 + kb * 32 + ((l >> 4) << 3)];
        bf16x8 A1 = *(const bf16x8*)&hw1[(16 + (l & 15)) * NH1 + kb * 32 + ((l >> 4) << 3)];
#pragma unroll
        for (int c2 = 0; c2 < 4; ++c2) {
            bf16x8 B = *(const bf16x8*)(w2f + (((c2 << 2) + kb) << 9) + l * 8);
            acc2[0][c2] = mfma16(A0, B, acc2[0][c2]);
            acc2[1][c2] = mfma16(A1, B, acc2[1][c2]);
        }
    }

    // ---------------- stage 3: z = h2 @ W3 + b3 ; conv sigmoid ------------
    float b2v[4];
#pragma unroll
    for (int c2 = 0; c2 < 4; ++c2) b2v[c2] = b2[c2 * 16 + (l & 15)];
    float w3l[4][4];
#pragma unroll
    for (int c2 = 0; c2 < 4; ++c2) {
        f32x4 t = *(const f32x4*)&W3[(c2 * 16 + (l & 15)) * 4];
        w3l[c2][0] = t.x; w3l[c2][1] = t.y; w3l[c2][2] = t.z; w3l[c2][3] = t.w;
    }
    float h2v[2][4][4];
#pragma unroll
    for (int g = 0; g < 2; ++g)
#pragma unroll
        for (int c2 = 0; c2 < 4; ++c2)
#pragma unroll
            for (int r = 0; r < 4; ++r)
                h2v[g][c2][r] = fmaxf(acc2[g][c2][r] + b2v[c2], 0.f);

    float pz[2][4][4];  // [g2][r][j] partial over this lane's 4 k-columns
#pragma unroll
    for (int g = 0; g < 2; ++g)
#pragma unroll
        for (int r = 0; r < 4; ++r)
#pragma unroll
            for (int j = 0; j < 4; ++j) {
                float s = 0.f;
#pragma unroll
                for (int c2 = 0; c2 < 4; ++c2) s = fmaf(h2v[g][c2][r], w3l[c2][j], s);
                pz[g][r][j] = s;
            }
    // reduce over the 16 lanes (l&15) that hold distinct k-columns
#pragma unroll
    for (int off = 1; off < 16; off <<= 1)
#pragma unroll
        for (int g = 0; g < 2; ++g)
#pragma unroll
            for (int r = 0; r < 4; ++r)
#pragma unroll
                for (int j = 0; j < 4; ++j)
                    pz[g][r][j] += __shfl_xor(pz[g][r][j], off, 64);

    const float ck0 = conv_k[0], ck1 = conv_k[1], ck2 = conv_k[2], ck3 = conv_k[3];
    const float cbv = conv_b[0];
    const float b30 = b3[0], b31 = b3[1], b32 = b3[2], b33 = b3[3];
    const float L2E = 1.44269504088896340736f;

    if ((l & 15) == 0) {
#pragma unroll
        for (int g = 0; g < 2; ++g)
#pragma unroll
            for (int r = 0; r < 4; ++r) {
                int rl = w * 32 + g * 16 + ((l >> 4) << 2) + r;
                float z0 = pz[g][r][0] + b30;
                float z1 = pz[g][r][1] + b31;
                float z2 = pz[g][r][2] + b32;
                float z3 = pz[g][r][3] + b33;
                float s = fmaf(z0, ck0, fmaf(z1, ck1, fmaf(z2, ck2, fmaf(z3, ck3, cbv))));
                float sg = 1.f / (1.f + expf(-s));
                float n2 = z0*z0 + z1*z1 + z2*z2 + z3*z3 + sg*sg;
                z5s[rl][0] = 2.f * L2E * z0;
                z5s[rl][1] = 2.f * L2E * z1;
                z5s[rl][2] = 2.f * L2E * z2;
                z5s[rl][3] = 2.f * L2E * z3;
                z5s[rl][4] = 2.f * L2E * sg;
                z5s[rl][5] = -L2E * n2;
            }
    }
    __syncthreads();

    // ---------------- stage 4: RBF + head ---------------------------------
    const int row = tid & 127;
    const int half = __builtin_amdgcn_readfirstlane(tid >> 7);
    f32x4 za = *(const f32x4*)&z5s[row][0];
    float z4s = z5s[row][4];
    float z5c = z5s[row][5];
    const float* bpp = bp + (size_t)half * 512 * 8;
    float accum = 0.f;
#pragma unroll 4
    for (int j = 0; j < 512; ++j) {
        f32x4 q0 = *(const f32x4*)&bpp[j * 8];
        f32x4 q1 = *(const f32x4*)&bpp[j * 8 + 4];
        float arg = fmaf(za.x, q0.x,
                    fmaf(za.y, q0.y,
                    fmaf(za.z, q0.z,
                    fmaf(za.w, q0.w,
                    fmaf(z4s, q1.x, z5c)))));
        accum = fmaf(q1.z, exp2f(arg), accum);
    }
    if (half) psum[row] = accum;
    __syncthreads();
    if (!half) out[blockIdx.x * 128 + row] = accum + psum[row] + head_b[0];
}

// ---------------------------------------------------------------------------
extern "C" void kernel_launch(void* const* d_in, const int* in_sizes, int n_in,
                              void* d_out, int out_size, void* d_ws, size_t ws_size,
                              hipStream_t stream) {
    const float* x     = (const float*)d_in[0];
    const float* W1    = (const float*)d_in[1];
    const float* b1    = (const float*)d_in[2];
    const float* W2    = (const float*)d_in[3];
    const float* b2    = (const float*)d_in[4];
    const float* W3    = (const float*)d_in[5];
    const float* b3    = (const float*)d_in[6];
    const float* ck    = (const float*)d_in[7];
    const float* cb    = (const float*)d_in[8];
    const float* basis = (const float*)d_in[9];
    const float* hwv   = (const float*)d_in[10];
    const float* hb    = (const float*)d_in[11];

    __bf16* w1f = (__bf16*)d_ws;                                 // 524288 B
    __bf16* w2f = (__bf16*)((char*)d_ws + 524288);               // 16384 B
    float*  bpp = (float*)((char*)d_ws + 524288 + 16384);        // 32768 B

    prep_kernel<<<1024, 256, 0, stream>>>(W1, W2, basis, hwv, w1f, w2f, bpp);
    fused_main<<<512, 256, 0, stream>>>(x, w1f, b1, w2f, b2, W3, b3, ck, cb,
                                        bpp, hb, (float*)d_out);
}